// Round 2
// baseline (1318.251 us; speedup 1.0000x reference)
//
#include <hip/hip_runtime.h>
#include <cstdint>
#include <cstddef>

#define DEV __device__ __forceinline__

typedef unsigned short u16;
typedef unsigned int   u32;
typedef __attribute__((ext_vector_type(8))) short bf16x8;
typedef __attribute__((ext_vector_type(4))) float f32x4;

static constexpr int NROWS = 50000;
static constexpr int FEAT  = 2048;
static constexpr int HID   = 1024;
static constexpr int DATT  = 512;
static constexpr int TXTD  = 768;

// ---------- helpers ----------
DEV u32 bfbits(float f) {                      // fp32 -> bf16 bits, round-to-nearest-even
  u32 u = __float_as_uint(f);
  return (u + 0x7fffu + ((u >> 16) & 1u)) >> 16;
}
DEV u32 pk2(float lo, float hi) { return bfbits(lo) | (bfbits(hi) << 16); }
DEV float bflo(u32 u) { return __uint_as_float(u << 16); }
DEV float bfhi(u32 u) { return __uint_as_float(u & 0xffff0000u); }

// async global->LDS, 16B per lane; lds dst is WAVE-UNIFORM base (HW adds lane*16)
DEV void gld_lds16(const u16* g, u16* l) {
  __builtin_amdgcn_global_load_lds(
      (const __attribute__((address_space(1))) unsigned int*)g,
      (__attribute__((address_space(3))) unsigned int*)l, 16, 0, 0);
}

// ---------- K1a: W1 [FEAT][HID] -> bf16 W1T [HID][FEAT] ----------
__global__ void k_t_w1(const float* __restrict__ W, u16* __restrict__ out) {
  __shared__ float tile[64][65];
  const int KT = FEAT / 64;                    // 32
  int bid = blockIdx.x;
  int kt = bid % KT, nt = bid / KT;
  int k0 = kt * 64, n0 = nt * 64;
  int t = threadIdx.x;
#pragma unroll
  for (int i = 0; i < 16; i++) {
    int idx = t + i * 256;
    int kk = idx >> 6, nn = idx & 63;
    tile[kk][nn] = W[(size_t)(k0 + kk) * HID + n0 + nn];
  }
  __syncthreads();
#pragma unroll
  for (int i = 0; i < 16; i++) {
    int idx = t + i * 256;
    int nn = idx >> 6, kk = idx & 63;
    out[(size_t)(n0 + nn) * FEAT + k0 + kk] = (u16)bfbits(tile[kk][nn]);
  }
}

// ---------- K1b: interleave Wa|Wb [HID][DATT] -> bf16 WgT [2*DATT][HID] ----------
// output row n: n=2j -> Wa[:,j], n=2j+1 -> Wb[:,j]
__global__ void k_t_wab(const float* __restrict__ Wa, const float* __restrict__ Wb,
                        u16* __restrict__ out) {
  __shared__ float tile[64][65];
  const int KT = HID / 64;                     // 16
  int bid = blockIdx.x;
  int kt = bid % KT, nt = bid / KT;
  int k0 = kt * 64, n0 = nt * 64;
  int t = threadIdx.x;
#pragma unroll
  for (int i = 0; i < 16; i++) {
    int idx = t + i * 256;
    int kk = idx >> 6, nn = idx & 63;
    int n = n0 + nn;
    const float* src = (n & 1) ? Wb : Wa;
    tile[kk][nn] = src[(size_t)(k0 + kk) * DATT + (n >> 1)];
  }
  __syncthreads();
#pragma unroll
  for (int i = 0; i < 16; i++) {
    int idx = t + i * 256;
    int nn = idx >> 6, kk = idx & 63;
    out[(size_t)(n0 + nn) * HID + k0 + kk] = (u16)bfbits(tile[kk][nn]);
  }
}

// ---------- shared MFMA tile compute: 128x128 tile, BK=64, 4 waves x (64x64) ----------
// LDS layout per operand: [row 0..127][64 k bf16 = 8 x 16B slots], slot XOR-swizzled by (row&7)
DEV void tile_mfma(const char* bufA, const char* bufB, f32x4 acc[4][4],
                   int lo, int hi, int wr, int wc) {
#pragma unroll
  for (int ks = 0; ks < 2; ks++) {
    bf16x8 av[4], bv[4];
#pragma unroll
    for (int m = 0; m < 4; m++) {
      int row = wr * 64 + m * 16 + lo;
      int off = (row * 128 + ks * 64 + hi * 16) ^ ((row & 7) << 4);
      av[m] = *(const bf16x8*)(bufA + off);
    }
#pragma unroll
    for (int n = 0; n < 4; n++) {
      int col = wc * 64 + n * 16 + lo;
      int off = (col * 128 + ks * 64 + hi * 16) ^ ((col & 7) << 4);
      bv[n] = *(const bf16x8*)(bufB + off);
    }
#pragma unroll
    for (int m = 0; m < 4; m++)
#pragma unroll
      for (int n = 0; n < 4; n++)
        acc[m][n] = __builtin_amdgcn_mfma_f32_16x16x32_bf16(av[m], bv[n], acc[m][n], 0, 0, 0);
  }
}

// ---------- GEMM1: Hb = relu(x @ W1 + b1) in bf16 ----------
// A (x, fp32): reg-staged with fused fp32->bf16 convert, swizzled ds_write.
// B (W1T, bf16): global_load_lds direct, swizzle folded into per-lane SOURCE addr (m173).
__global__ __launch_bounds__(256, 2) void k_gemm1(const float* __restrict__ X,
                                                  const u16* __restrict__ BT,
                                                  const float* __restrict__ b1,
                                                  u16* __restrict__ Hb) {
  __shared__ __align__(16) char smem[2][32768];   // per buf: A 16KB | B 16KB
  int t = threadIdx.x;
  int l = t & 63, w = t >> 6;
  int lo = l & 15, hi = l >> 4;
  int wr = w >> 1, wc = w & 1;

  int nwg = gridDim.x, bid = blockIdx.x;
  int li = ((nwg & 7) == 0) ? ((bid & 7) * (nwg >> 3) + (bid >> 3)) : bid;  // XCD swizzle
  int mt = li >> 3, nt = li & 7;                   // nt-minor: A-panel reuse within XCD L2
  int rowbase = mt * 128, ncb0 = nt * 128;

  f32x4 acc[4][4];
#pragma unroll
  for (int m = 0; m < 4; m++)
#pragma unroll
    for (int n = 0; n < 4; n++) acc[m][n] = {0.f, 0.f, 0.f, 0.f};

  const int KT = FEAT / 64;                        // 32

  auto stageB = [&](int kt_, int buf) {            // async, non-blocking
    int kbase = kt_ * 64;
    char* bufB = smem[buf] + 16384;
#pragma unroll
    for (int i = 0; i < 4; i++) {
      int s = t + i * 256;
      int nn = s >> 3, k8 = (s & 7) ^ (nn & 7);    // inverse-swizzled source
      const u16* src = BT + (size_t)(ncb0 + nn) * FEAT + kbase + k8 * 8;
      u16* dst = (u16*)(bufB + i * 4096 + w * 1024);  // wave-uniform
      gld_lds16(src, dst);
    }
  };
  auto stageA = [&](int kt_, int buf) {            // reg-staged (fp32->bf16)
    int kbase = kt_ * 64;
    char* bufA = smem[buf];
#pragma unroll
    for (int i = 0; i < 4; i++) {
      int s = t + i * 256;
      int row = s >> 3, k8 = s & 7;
      int grow = rowbase + row; if (grow >= NROWS) grow = NROWS - 1;
      const float4* src = (const float4*)(X + (size_t)grow * FEAT + kbase + k8 * 8);
      float4 f0 = src[0], f1 = src[1];
      uint4 v; v.x = pk2(f0.x, f0.y); v.y = pk2(f0.z, f0.w);
      v.z = pk2(f1.x, f1.y); v.w = pk2(f1.z, f1.w);
      int off = (row * 128 + k8 * 16) ^ ((row & 7) << 4);
      *(uint4*)(bufA + off) = v;
    }
  };

  stageB(0, 0);
  stageA(0, 0);
  __syncthreads();
  for (int kt_ = 0; kt_ < KT - 1; ++kt_) {
    int nb = (kt_ + 1) & 1;
    stageB(kt_ + 1, nb);                           // issue async loads first
    stageA(kt_ + 1, nb);
    tile_mfma(smem[kt_ & 1], smem[kt_ & 1] + 16384, acc, lo, hi, wr, wc);
    __syncthreads();
  }
  tile_mfma(smem[(KT - 1) & 1], smem[(KT - 1) & 1] + 16384, acc, lo, hi, wr, wc);

  int mrow0 = rowbase + wr * 64;
  int ncol0 = ncb0 + wc * 64;
#pragma unroll
  for (int n = 0; n < 4; n++) {
    int col = ncol0 + n * 16 + lo;
    float bias = b1[col];
#pragma unroll
    for (int m = 0; m < 4; m++)
#pragma unroll
      for (int i = 0; i < 4; i++) {
        int row = mrow0 + m * 16 + hi * 4 + i;
        if (row < NROWS) {
          float v = acc[m][n][i] + bias;
          v = fmaxf(v, 0.f);
          Hb[(size_t)row * HID + col] = (u16)bfbits(v);
        }
      }
  }
}

// ---------- GEMM2: scores[r] += sum_j tanh(h@Wa+ba)*sigmoid(h@Wb+bb)*Wc ----------
// Both operands bf16 -> both staged via global_load_lds with source-folded swizzle.
__global__ __launch_bounds__(256, 2) void k_gemm2(const u16* __restrict__ Hb,
                                                  const u16* __restrict__ BT,
                                                  const float* __restrict__ ba,
                                                  const float* __restrict__ bb,
                                                  const float* __restrict__ Wc,
                                                  float* __restrict__ scores) {
  __shared__ __align__(16) char smem[2][32768];
  int t = threadIdx.x;
  int l = t & 63, w = t >> 6;
  int lo = l & 15, hi = l >> 4;
  int wr = w >> 1, wc_ = w & 1;

  int nwg = gridDim.x, bid = blockIdx.x;
  int li = ((nwg & 7) == 0) ? ((bid & 7) * (nwg >> 3) + (bid >> 3)) : bid;
  int mt = li >> 3, nt = li & 7;                   // N = 1024 interleaved a|g cols
  int rowbase = mt * 128, ncb0 = nt * 128;

  f32x4 acc[4][4];
#pragma unroll
  for (int m = 0; m < 4; m++)
#pragma unroll
    for (int n = 0; n < 4; n++) acc[m][n] = {0.f, 0.f, 0.f, 0.f};

  const int KT = HID / 64;                         // 16

  auto stage = [&](int kt_, int buf) {             // fully async (A and B)
    int kbase = kt_ * 64;
    char* bufA = smem[buf];
    char* bufB = smem[buf] + 16384;
#pragma unroll
    for (int i = 0; i < 4; i++) {
      int s = t + i * 256;
      int nn = s >> 3, k8 = (s & 7) ^ (nn & 7);    // inverse-swizzled source
      int grow = rowbase + nn; if (grow >= NROWS) grow = NROWS - 1;
      gld_lds16(Hb + (size_t)grow * HID + kbase + k8 * 8,
                (u16*)(bufA + i * 4096 + w * 1024));
      gld_lds16(BT + (size_t)(ncb0 + nn) * HID + kbase + k8 * 8,
                (u16*)(bufB + i * 4096 + w * 1024));
    }
  };

  stage(0, 0);
  __syncthreads();
  for (int kt_ = 0; kt_ < KT - 1; ++kt_) {
    stage(kt_ + 1, (kt_ + 1) & 1);
    tile_mfma(smem[kt_ & 1], smem[kt_ & 1] + 16384, acc, lo, hi, wr, wc_);
    __syncthreads();
  }
  tile_mfma(smem[(KT - 1) & 1], smem[(KT - 1) & 1] + 16384, acc, lo, hi, wr, wc_);

  // fused gated-attention epilogue
  int mrow0 = rowbase + wr * 64;
  int ncol0 = ncb0 + wc_ * 64;
  float rs[4][4];
#pragma unroll
  for (int m = 0; m < 4; m++)
#pragma unroll
    for (int i = 0; i < 4; i++) rs[m][i] = 0.f;

#pragma unroll
  for (int n = 0; n < 4; n++) {
    int col = ncol0 + n * 16 + lo;
    int j = col >> 1;
    bool odd = (col & 1);                          // even col -> tanh branch, odd -> sigmoid
    float bias = odd ? bb[j] : ba[j];
    float wcj = Wc[j];
    float scl  = odd ? 0.5f : 1.0f;                // sigmoid(v) = 0.5*tanh(v/2)+0.5
    float pmul = odd ? 0.5f : 1.0f;
    float padd = odd ? 0.5f : 0.0f;
#pragma unroll
    for (int m = 0; m < 4; m++)
#pragma unroll
      for (int i = 0; i < 4; i++) {
        float v = acc[m][n][i] + bias;
        float act = fmaf(tanhf(v * scl), pmul, padd);
        float prt = __shfl_xor(act, 1);            // partner activation (paired column)
        rs[m][i] = fmaf(act * prt, wcj, rs[m][i]);
      }
  }
#pragma unroll
  for (int m = 0; m < 4; m++)
#pragma unroll
    for (int i = 0; i < 4; i++) {
      float sv = rs[m][i];
      sv += __shfl_xor(sv, 2);
      sv += __shfl_xor(sv, 4);
      sv += __shfl_xor(sv, 8);                     // even lanes cover each pair exactly once
      if (lo == 0) {
        int row = mrow0 + m * 16 + hi * 4 + i;
        if (row < NROWS) atomicAdd(&scores[row], sv);
      }
    }
}

// ---------- softmax reductions ----------
__global__ void k_red1(const float* __restrict__ s, int n, float2* __restrict__ part) {
  __shared__ float sm[256];
  int t = threadIdx.x;
  int stride = gridDim.x * 256;
  float m = -3.4e38f;
  for (int i = blockIdx.x * 256 + t; i < n; i += stride) m = fmaxf(m, s[i]);
  sm[t] = m; __syncthreads();
  for (int st = 128; st; st >>= 1) { if (t < st) sm[t] = fmaxf(sm[t], sm[t + st]); __syncthreads(); }
  float bm = sm[0];
  __syncthreads();
  float se = 0.f;
  for (int i = blockIdx.x * 256 + t; i < n; i += stride) se += expf(s[i] - bm);
  sm[t] = se; __syncthreads();
  for (int st = 128; st; st >>= 1) { if (t < st) sm[t] += sm[t + st]; __syncthreads(); }
  if (t == 0) part[blockIdx.x] = make_float2(bm, sm[0]);
}

__global__ void k_red2(const float2* __restrict__ part, float* __restrict__ red2) {
  int t = threadIdx.x;                             // 64 threads = 1 wave
  float2 p = part[t];
  float m = p.x;
#pragma unroll
  for (int off = 32; off; off >>= 1) m = fmaxf(m, __shfl_down(m, off));
  m = __shfl(m, 0);
  float se = p.y * expf(p.x - m);
#pragma unroll
  for (int off = 32; off; off >>= 1) se += __shfl_down(se, off);
  if (t == 0) { red2[0] = m; red2[1] = se; }
}

// ---------- pooled M = softmax(scores) @ h ----------
__global__ void k_pool(const u16* __restrict__ Hb, const float* __restrict__ scores,
                       const float* __restrict__ red2, float* __restrict__ Mpool) {
  int t = threadIdx.x;
  int c = t * 4;
  float gmax = red2[0];
  float ginv = 1.0f / red2[1];
  float a0 = 0, a1 = 0, a2 = 0, a3 = 0;
  int r0 = blockIdx.x * 128;
  int rend = r0 + 128; if (rend > NROWS) rend = NROWS;
  for (int r = r0; r < rend; ++r) {
    float wgt = expf(scores[r] - gmax) * ginv;
    uint2 hv = *(const uint2*)(Hb + (size_t)r * HID + c);
    a0 = fmaf(wgt, bflo(hv.x), a0);
    a1 = fmaf(wgt, bfhi(hv.x), a1);
    a2 = fmaf(wgt, bflo(hv.y), a2);
    a3 = fmaf(wgt, bfhi(hv.y), a3);
  }
  atomicAdd(&Mpool[c + 0], a0);
  atomicAdd(&Mpool[c + 1], a1);
  atomicAdd(&Mpool[c + 2], a2);
  atomicAdd(&Mpool[c + 3], a3);
}

// ---------- text branch + logits ----------
__global__ void k_final(const float* __restrict__ Mpool, const float* __restrict__ text,
                        const float* __restrict__ Wt, const float* __restrict__ bt,
                        const float* __restrict__ Wcls, const float* __restrict__ bcls,
                        float* __restrict__ out) {
  __shared__ float Mv[HID];
  __shared__ float red0[256], red1[256];
  int t = threadIdx.x;
#pragma unroll
  for (int rep = 0; rep < 4; rep++) {
    int n = t + rep * 256;
    float accv = bt[n];
    for (int k = 0; k < TXTD; k++) accv = fmaf(text[k], Wt[(size_t)k * HID + n], accv);
    accv = fmaxf(accv, 0.f);
    Mv[n] = Mpool[n] + accv;
  }
  __syncthreads();
  float p0 = 0.f, p1 = 0.f;
#pragma unroll
  for (int rep = 0; rep < 4; rep++) {
    int n = t + rep * 256;
    p0 = fmaf(Mv[n], Wcls[n * 2 + 0], p0);
    p1 = fmaf(Mv[n], Wcls[n * 2 + 1], p1);
  }
  red0[t] = p0; red1[t] = p1;
  __syncthreads();
  for (int st = 128; st; st >>= 1) {
    if (t < st) { red0[t] += red0[t + st]; red1[t] += red1[t + st]; }
    __syncthreads();
  }
  if (t == 0) { out[0] = red0[0] + bcls[0]; out[1] = red1[0] + bcls[1]; }
}

// ---------- launch ----------
extern "C" void kernel_launch(void* const* d_in, const int* in_sizes, int n_in,
                              void* d_out, int out_size, void* d_ws, size_t ws_size,
                              hipStream_t stream) {
  const float* x    = (const float*)d_in[0];
  const float* text = (const float*)d_in[1];
  const float* W1   = (const float*)d_in[2];
  const float* b1   = (const float*)d_in[3];
  const float* Wa   = (const float*)d_in[4];
  const float* ba   = (const float*)d_in[5];
  const float* Wb   = (const float*)d_in[6];
  const float* bb   = (const float*)d_in[7];
  const float* Wc   = (const float*)d_in[8];
  // d_in[9] = bc: uniform shift on pre-softmax scores -> dropped (softmax invariant)
  const float* Wt   = (const float*)d_in[10];
  const float* bt   = (const float*)d_in[11];
  const float* Wcls = (const float*)d_in[12];
  const float* bcls = (const float*)d_in[13];

  // workspace layout (bytes)
  const size_t off_w1t = 0;                          // 1024*2048*2 = 4,194,304
  const size_t off_wg  = 4194304;                    // 1024*1024*2 = 2,097,152
  const size_t off_hb  = 6291456;                    // 50000*1024*2 = 102,400,000
  const size_t off_sc  = 108691456;                  // 50000*4
  const size_t off_pt  = 108891456;                  // 64*8
  const size_t off_r2  = 108891968;                  // 8
  const size_t off_m   = 108892032;                  // 1024*4
  const size_t NEED    = 108896128;
  if (ws_size < NEED) return;

  char* ws = (char*)d_ws;
  u16*   W1T    = (u16*)(ws + off_w1t);
  u16*   WgT    = (u16*)(ws + off_wg);
  u16*   Hb     = (u16*)(ws + off_hb);
  float* scores = (float*)(ws + off_sc);
  float2* part  = (float2*)(ws + off_pt);
  float* red2   = (float*)(ws + off_r2);
  float* Mpool  = (float*)(ws + off_m);

  hipMemsetAsync(scores, 0, NROWS * sizeof(float), stream);
  hipMemsetAsync(Mpool, 0, HID * sizeof(float), stream);

  k_t_w1 <<<(FEAT / 64) * (HID / 64), 256, 0, stream>>>(W1, W1T);
  k_t_wab<<<(HID / 64) * (HID / 64),  256, 0, stream>>>(Wa, Wb, WgT);

  const int MT = (NROWS + 127) / 128;                // 391
  k_gemm1<<<MT * 8, 256, 0, stream>>>(x, W1T, b1, Hb);
  k_gemm2<<<MT * 8, 256, 0, stream>>>(Hb, WgT, ba, bb, Wc, scores);

  k_red1<<<64, 256, 0, stream>>>(scores, NROWS, part);
  k_red2<<<1, 64, 0, stream>>>(part, red2);
  k_pool<<<MT, 256, 0, stream>>>(Hb, scores, red2, Mpool);
  k_final<<<1, 256, 0, stream>>>(Mpool, text, Wt, bt, Wcls, bcls, (float*)d_out);
}